// Round 8
// baseline (135.419 us; speedup 1.0000x reference)
//
#include <hip/hip_runtime.h>
#include <math.h>

// B=1, S=4096, H=8, DH=40, D=320, fp32 in/out.  THREE kernels:
// proj_qkv: MFMA GEMM (fp32->bf16 staging, reg prefetch) -> Qp/Kp [h][s][48]
//           (Q pre-scaled; pad carries -32 offset trick), Vt [h][40][4096];
//           epilogues go through an LDS tile -> coalesced 16B stores.
// attn:     MFMA flash (R6 verbatim): ks=8 key split, sigma-permuted K so
//           QK C/D regs ARE PV A-frags, p = raw v_exp_f32, l via ones-row.
// proj_out: MFMA GEMM + bias; A-staging fuses the 8-partial combine
//           (unpack-sum-normalize via invL LDS table). No combine kernel.

#define NS 4096
#define ND 320
#define SCALE2 0.2281101152f      // log2(e)/sqrt(40)
#define HS48 196608               // 4096*48 per head
#define VTH 163840                // 40*4096 per head
#define XN 1310720

typedef __attribute__((ext_vector_type(8))) short bf16x8;
typedef __attribute__((ext_vector_type(16))) float f32x16;

// round-half-up f32->bf16 (ties differ from RNE with prob ~2^-16)
static __device__ __forceinline__ unsigned short f2bru(float f) {
  return (unsigned short)((__builtin_bit_cast(unsigned int, f) + 0x8000u) >> 16);
}
static __device__ __forceinline__ unsigned int pk2ru(float a, float b) {
  unsigned int ua = __builtin_bit_cast(unsigned int, a) + 0x8000u;
  unsigned int ub = __builtin_bit_cast(unsigned int, b) + 0x8000u;
  return __builtin_amdgcn_perm(ub, ua, 0x07060302u);
}
// 1-inst truncating pack (bias cancels through softmax denominator)
static __device__ __forceinline__ unsigned int pk2t(float a, float b) {
  return __builtin_amdgcn_perm(__builtin_bit_cast(unsigned int, b),
                               __builtin_bit_cast(unsigned int, a), 0x07060302u);
}
static __device__ __forceinline__ float fexp2(float x) {
  return __builtin_amdgcn_exp2f(x);
}
static __device__ __forceinline__ bf16x8 ld8(const unsigned short* p) {
  union { uint2 u[2]; bf16x8 v; } c;
  c.u[0] = *(const uint2*)p;
  c.u[1] = *(const uint2*)(p + 4);
  return c.v;
}
static __device__ __forceinline__ uint4 ld16u(const unsigned short* p) {
  uint2 a = *(const uint2*)p, b = *(const uint2*)(p + 4);
  return make_uint4(a.x, a.y, b.x, b.y);
}
static __device__ __forceinline__ void st16(unsigned short* p, uint4 v) {
  *(uint2*)p = make_uint2(v.x, v.y);
  *(uint2*)(p + 4) = make_uint2(v.z, v.w);
}
// sigma: phys key (0..31) -> MFMA m-row so QK C/D regs land in PV A order
static __device__ __forceinline__ int sig32(int q) {
  int s = q >> 4, h2 = (q >> 3) & 1, j = q & 7;
  return (s << 4) | ((j >> 2) << 3) | (h2 << 2) | (j & 3);
}

// ---------------------------------------------------------------------------
// Kernel 1: q/k/v = x @ W^T via MFMA. grid (64,5,3) x 256.
// ---------------------------------------------------------------------------
__global__ __launch_bounds__(256) void proj_qkv_kernel(
    const float* __restrict__ x, const float* __restrict__ Wq,
    const float* __restrict__ Wk, const float* __restrict__ Wv,
    unsigned short* __restrict__ Qp, unsigned short* __restrict__ Kp,
    unsigned short* __restrict__ Vt) {
  const int z = blockIdx.z;
  const float* W = (z == 0) ? Wq : (z == 1) ? Wk : Wv;
  __shared__ __align__(16) unsigned short As[64 * 36];
  __shared__ __align__(16) unsigned short Bs[64 * 36];
  __shared__ __align__(16) unsigned short Tile[64 * 76];  // epilogue staging
  const int t = threadIdx.x;
  const int w = t >> 6, l = t & 63, l31 = l & 31, hi = l >> 5;
  const int bm = blockIdx.x * 64, bn = blockIdx.y * 64;
  const int m0 = (w & 1) * 32, n0 = (w >> 1) * 32;
  f32x16 acc = {0,0,0,0,0,0,0,0,0,0,0,0,0,0,0,0};
  const int ar = t >> 2, ac = t & 3;
  const float* gA = x + (bm + ar) * ND + ac * 8;
  const float* gB = W + (bn + ar) * ND + ac * 8;
  unsigned short* lA = As + ar * 36 + ac * 8;
  unsigned short* lB = Bs + ar * 36 + ac * 8;
  const unsigned short* af = As + (m0 + l31) * 36 + hi * 8;
  const unsigned short* bf = Bs + (n0 + l31) * 36 + hi * 8;
  float4 a0 = *(const float4*)gA, a1 = *(const float4*)(gA + 4);
  float4 b0 = *(const float4*)gB, b1 = *(const float4*)(gB + 4);
  for (int k0 = 0; k0 < ND; k0 += 32) {
    __syncthreads();
    st16(lA, make_uint4(pk2ru(a0.x, a0.y), pk2ru(a0.z, a0.w),
                        pk2ru(a1.x, a1.y), pk2ru(a1.z, a1.w)));
    st16(lB, make_uint4(pk2ru(b0.x, b0.y), pk2ru(b0.z, b0.w),
                        pk2ru(b1.x, b1.y), pk2ru(b1.z, b1.w)));
    __syncthreads();
    if (k0 + 32 < ND) {                      // prefetch next tile -> regs
      gA += 32; gB += 32;
      a0 = *(const float4*)gA; a1 = *(const float4*)(gA + 4);
      b0 = *(const float4*)gB; b1 = *(const float4*)(gB + 4);
    }
    bf16x8 A0 = ld8(af), A1 = ld8(af + 16);
    bf16x8 B0 = ld8(bf), B1 = ld8(bf + 16);
    acc = __builtin_amdgcn_mfma_f32_32x32x16_bf16(A0, B0, acc, 0, 0, 0);
    acc = __builtin_amdgcn_mfma_f32_32x32x16_bf16(A1, B1, acc, 0, 0, 0);
  }
  if (z < 2) {
    // ---- Q/K epilogue: LDS tile [row][j], stride 68 -> coalesced 16B ----
    unsigned short* Y = (z == 0) ? Qp : Kp;
    const float sc = (z == 0) ? SCALE2 : 1.0f;
    const unsigned int padw = (z == 0) ? 0xC200u : 0x3F80u;  // -32.0 : 1.0
#pragma unroll
    for (int r2 = 0; r2 < 16; r2++) {
      int lr = m0 + (r2 & 3) + 8 * (r2 >> 2) + 4 * hi;
      Tile[lr * 68 + n0 + l31] = f2bru(acc[r2] * sc);
    }
    __syncthreads();
    for (int i = t; i < 512; i += 256) {     // 64 rows x 8 chunks(8 shorts)
      int row = i >> 3, ch = i & 7;
      int j = bn + ch * 8;
      int h = j / 40, dh = j - h * 40;
      uint4 v = ld16u(Tile + row * 68 + ch * 8);
      unsigned short* dst = Y + h * HS48 + (bm + row) * 48 + dh;
      st16(dst, v);
      if (dh == 0)                           // pad chunk {padv,0,...} at +40
        st16(Y + h * HS48 + (bm + row) * 48 + 40, make_uint4(padw, 0u, 0u, 0u));
    }
  } else {
    // ---- V epilogue: transposed LDS tile [j][row], stride 76 ----
#pragma unroll
    for (int r2 = 0; r2 < 16; r2++) {
      int lr = m0 + (r2 & 3) + 8 * (r2 >> 2) + 4 * hi;
      Tile[(n0 + l31) * 76 + lr] = f2bru(acc[r2]);
    }
    __syncthreads();
    for (int i = t; i < 512; i += 256) {     // 64 j-rows x 8 s-chunks
      int row = i >> 3, ch = i & 7;
      int j = bn + row;
      int h = j / 40, dd = j - h * 40;
      uint4 v = ld16u(Tile + row * 76 + ch * 8);
      st16(Vt + h * VTH + dd * NS + bm + ch * 8, v);
    }
  }
}

// ---------------------------------------------------------------------------
// Kernel 2: MFMA flash attention (R6 verbatim). grid 2048 x 256.
// ---------------------------------------------------------------------------
__global__ __launch_bounds__(256) void attn_kernel(
    const unsigned short* __restrict__ Qp, const unsigned short* __restrict__ Kp,
    const unsigned short* __restrict__ Vt, unsigned short* __restrict__ Op,
    float* __restrict__ Lp) {
  const int b = blockIdx.x;
  const int h = b & 7, ks = (b >> 3) & 7, qt = b >> 6;
  const int t = threadIdx.x;
  const int w = t >> 6, l = t & 63, l31 = l & 31, hi = l >> 5;
  __shared__ __align__(16) unsigned short Ks[64 * 68];   // [m-row][48 used]
  __shared__ __align__(16) unsigned short Vs[48 * 68];   // [dh][64 keys]
  for (int i = t; i < 272; i += 256)
    ((unsigned int*)(Vs + 40 * 68))[i] = (i < 34) ? 0x3F803F80u : 0u;

  const int kbase = ks * 512;
  const int qbase = qt * 128 + w * 32;
  const unsigned short* qp = Qp + h * HS48 + (qbase + l31) * 48 + hi * 8;
  bf16x8 qf0 = *(const bf16x8*)qp;
  bf16x8 qf1 = *(const bf16x8*)(qp + 16);
  bf16x8 qf2 = *(const bf16x8*)(qp + 32);   // includes {-32,0..} pad

  f32x16 oa0 = {0,0,0,0,0,0,0,0,0,0,0,0,0,0,0,0};
  f32x16 oa1 = {0,0,0,0,0,0,0,0,0,0,0,0,0,0,0,0};

  const int kr0 = t / 6, kc0 = t - kr0 * 6;
  const int kr1 = (t + 256) / 6, kc1 = (t + 256) - kr1 * 6;
  const unsigned short* gK0 = Kp + h * HS48 + (kbase + kr0) * 48 + kc0 * 8;
  const unsigned short* gK1 = Kp + h * HS48 + (kbase + kr1) * 48 + kc1 * 8;
  unsigned short* lK0 = Ks + ((kr0 & 32) | sig32(kr0 & 31)) * 68 + kc0 * 8;
  unsigned short* lK1 = Ks + ((kr1 & 32) | sig32(kr1 & 31)) * 68 + kc1 * 8;
  const int vr0 = t >> 3, vc = t & 7, vr1 = 32 + vr0;
  const unsigned short* gV0 = Vt + h * VTH + vr0 * NS + kbase + vc * 8;
  const unsigned short* gV1 = Vt + h * VTH + vr1 * NS + kbase + vc * 8;
  unsigned short* lV0 = Vs + vr0 * 68 + vc * 8;
  unsigned short* lV1 = Vs + vr1 * 68 + vc * 8;

  const unsigned short* kf0 = Ks + l31 * 68 + hi * 8;
  const unsigned short* kf1 = Ks + (32 + l31) * 68 + hi * 8;
  const unsigned short* vf0 = Vs + l31 * 68 + hi * 8;
  const unsigned short* vf1 = Vs + (32 + (l31 & 15)) * 68 + hi * 8;

  uint4 ka = *(const uint4*)gK0;
  uint4 kb2, vb2;
  uint4 va = *(const uint4*)gV0;
  if (t < 128) kb2 = *(const uint4*)gK1;
  if (t < 64)  vb2 = *(const uint4*)gV1;

  for (int it = 0; it < 8; ++it) {
    __syncthreads();
    st16(lK0, ka);
    if (t < 128) st16(lK1, kb2);
    st16(lV0, va);
    if (t < 64) st16(lV1, vb2);
    __syncthreads();
    // prefetch next tile (last-iter overrun lands in adjacent ws buffers)
    gK0 += 64 * 48; gK1 += 64 * 48; gV0 += 64; gV1 += 64;
    ka = *(const uint4*)gK0;
    va = *(const uint4*)gV0;
    if (t < 128) kb2 = *(const uint4*)gK1;
    if (t < 64)  vb2 = *(const uint4*)gV1;

    unsigned int pw0[8], pw1[8];
    {  // m-tile 0: phys keys 0..31 (sigma rows)
      f32x16 s0 = {0,0,0,0,0,0,0,0,0,0,0,0,0,0,0,0};
      s0 = __builtin_amdgcn_mfma_f32_32x32x16_bf16(ld8(kf0), qf0, s0, 0, 0, 0);
      s0 = __builtin_amdgcn_mfma_f32_32x32x16_bf16(ld8(kf0 + 16), qf1, s0, 0, 0, 0);
      s0 = __builtin_amdgcn_mfma_f32_32x32x16_bf16(ld8(kf0 + 32), qf2, s0, 0, 0, 0);
#pragma unroll
      for (int i = 0; i < 8; i++)
        pw0[i] = pk2t(fexp2(s0[2 * i]), fexp2(s0[2 * i + 1]));
    }
    {  // m-tile 1: phys keys 32..63
      f32x16 s1 = {0,0,0,0,0,0,0,0,0,0,0,0,0,0,0,0};
      s1 = __builtin_amdgcn_mfma_f32_32x32x16_bf16(ld8(kf1), qf0, s1, 0, 0, 0);
      s1 = __builtin_amdgcn_mfma_f32_32x32x16_bf16(ld8(kf1 + 16), qf1, s1, 0, 0, 0);
      s1 = __builtin_amdgcn_mfma_f32_32x32x16_bf16(ld8(kf1 + 32), qf2, s1, 0, 0, 0);
#pragma unroll
      for (int i = 0; i < 8; i++)
        pw1[i] = pk2t(fexp2(s1[2 * i]), fexp2(s1[2 * i + 1]));
    }
    bf16x8 pf0 = __builtin_bit_cast(bf16x8, make_uint4(pw0[0], pw0[1], pw0[2], pw0[3]));
    bf16x8 pf1 = __builtin_bit_cast(bf16x8, make_uint4(pw0[4], pw0[5], pw0[6], pw0[7]));
    bf16x8 pf2 = __builtin_bit_cast(bf16x8, make_uint4(pw1[0], pw1[1], pw1[2], pw1[3]));
    bf16x8 pf3 = __builtin_bit_cast(bf16x8, make_uint4(pw1[4], pw1[5], pw1[6], pw1[7]));
    oa0 = __builtin_amdgcn_mfma_f32_32x32x16_bf16(pf0, ld8(vf0), oa0, 0, 0, 0);
    oa1 = __builtin_amdgcn_mfma_f32_32x32x16_bf16(pf0, ld8(vf1), oa1, 0, 0, 0);
    oa0 = __builtin_amdgcn_mfma_f32_32x32x16_bf16(pf1, ld8(vf0 + 16), oa0, 0, 0, 0);
    oa1 = __builtin_amdgcn_mfma_f32_32x32x16_bf16(pf1, ld8(vf1 + 16), oa1, 0, 0, 0);
    oa0 = __builtin_amdgcn_mfma_f32_32x32x16_bf16(pf2, ld8(vf0 + 32), oa0, 0, 0, 0);
    oa1 = __builtin_amdgcn_mfma_f32_32x32x16_bf16(pf2, ld8(vf1 + 32), oa1, 0, 0, 0);
    oa0 = __builtin_amdgcn_mfma_f32_32x32x16_bf16(pf3, ld8(vf0 + 48), oa0, 0, 0, 0);
    oa1 = __builtin_amdgcn_mfma_f32_32x32x16_bf16(pf3, ld8(vf1 + 48), oa1, 0, 0, 0);
  }

  unsigned short* opb = Op + ks * XN + h * 163840;
  float* lpb = Lp + ks * 32768 + h * NS;
#pragma unroll
  for (int r2 = 0; r2 < 16; r2++) {
    int qr = qbase + (r2 & 3) + 8 * (r2 >> 2) + 4 * hi;
    opb[qr * 40 + l31] = f2bru(oa0[r2]);
    if (l31 < 8) opb[qr * 40 + 32 + l31] = f2bru(oa1[r2]);
    if (l31 == 8) lpb[qr] = oa1[r2];   // l = Sum(p) via ones-row at dh=40
  }
}

// ---------------------------------------------------------------------------
// Kernel 3: out = combine(Op,Lp) @ Wo^T + bo via MFMA. grid (64,5) x 256.
// A-staging fuses the 8-partial sum + normalization (combine kernel deleted).
// ---------------------------------------------------------------------------
__global__ __launch_bounds__(256) void proj_out_kernel(
    const unsigned short* __restrict__ Op, const float* __restrict__ Lp,
    const float* __restrict__ Wo, const float* __restrict__ bo,
    float* __restrict__ out) {
  __shared__ __align__(16) unsigned short As[64 * 36];
  __shared__ __align__(16) unsigned short Bs[64 * 36];
  __shared__ float invL[512];                // [h][s-local]
  const int t = threadIdx.x;
  const int w = t >> 6, l = t & 63, l31 = l & 31, hi = l >> 5;
  const int bm = blockIdx.x * 64, bn = blockIdx.y * 64;
  const int m0 = (w & 1) * 32, n0 = (w >> 1) * 32;
  f32x16 acc = {0,0,0,0,0,0,0,0,0,0,0,0,0,0,0,0};
  const int ar = t >> 2, ac = t & 3;

  for (int i = t; i < 512; i += 256) {       // build invL table
    int h2 = i >> 6, sl = i & 63;
    float ls = 0.f;
#pragma unroll
    for (int k = 0; k < 8; k++) ls += Lp[k * 32768 + h2 * NS + bm + sl];
    invL[i] = 1.0f / ls;
  }

  const float* gB = Wo + (bn + ar) * ND + ac * 8;
  unsigned short* lA = As + ar * 36 + ac * 8;
  unsigned short* lB = Bs + ar * 36 + ac * 8;
  const unsigned short* af = As + (m0 + l31) * 36 + hi * 8;
  const unsigned short* bf = Bs + (n0 + l31) * 36 + hi * 8;

  int d0 = ac * 8;
  int h2 = d0 / 40, dh = d0 - h2 * 40;
  const unsigned short* opb = Op + h2 * 163840 + (bm + ar) * 40 + dh;
  uint4 u[8];
#pragma unroll
  for (int k = 0; k < 8; k++) u[k] = *(const uint4*)(opb + k * XN);
  float4 b0 = *(const float4*)gB, b1 = *(const float4*)(gB + 4);

  for (int k0 = 0; k0 < ND; k0 += 32) {
    __syncthreads();
    {  // combine 8 partials -> normalized bf16 A chunk
      float a0 = 0.f, a1 = 0.f, a2 = 0.f, a3 = 0.f;
      float a4 = 0.f, a5 = 0.f, a6 = 0.f, a7 = 0.f;
#pragma unroll
      for (int k = 0; k < 8; k++) {
        a0 += __builtin_bit_cast(float, u[k].x << 16);
        a1 += __builtin_bit_cast(float, u[k].x & 0xFFFF0000u);
        a2 += __builtin_bit_cast(float, u[k].y << 16);
        a3 += __builtin_bit_cast(float, u[k].y & 0xFFFF0000u);
        a4 += __builtin_bit_cast(float, u[k].z << 16);
        a5 += __builtin_bit_cast(float, u[k].z & 0xFFFF0000u);
        a6 += __builtin_bit_cast(float, u[k].w << 16);
        a7 += __builtin_bit_cast(float, u[k].w & 0xFFFF0000u);
      }
      float inv = invL[h2 * 64 + ar];
      st16(lA, make_uint4(pk2ru(a0 * inv, a1 * inv), pk2ru(a2 * inv, a3 * inv),
                          pk2ru(a4 * inv, a5 * inv), pk2ru(a6 * inv, a7 * inv)));
    }
    st16(lB, make_uint4(pk2ru(b0.x, b0.y), pk2ru(b0.z, b0.w),
                        pk2ru(b1.x, b1.y), pk2ru(b1.z, b1.w)));
    __syncthreads();
    if (k0 + 32 < ND) {                      // prefetch next tile -> regs
      d0 += 32;
      h2 = d0 / 40; dh = d0 - h2 * 40;
      opb = Op + h2 * 163840 + (bm + ar) * 40 + dh;
#pragma unroll
      for (int k = 0; k < 8; k++) u[k] = *(const uint4*)(opb + k * XN);
      gB += 32;
      b0 = *(const float4*)gB; b1 = *(const float4*)(gB + 4);
    }
    bf16x8 A0 = ld8(af), A1 = ld8(af + 16);
    bf16x8 B0 = ld8(bf), B1 = ld8(bf + 16);
    acc = __builtin_amdgcn_mfma_f32_32x32x16_bf16(A0, B0, acc, 0, 0, 0);
    acc = __builtin_amdgcn_mfma_f32_32x32x16_bf16(A1, B1, acc, 0, 0, 0);
  }
  const int j = bn + n0 + l31;
  const float bj = bo[j];
#pragma unroll
  for (int r2 = 0; r2 < 16; r2++) {
    int row = bm + m0 + (r2 & 3) + 8 * (r2 >> 2) + 4 * hi;
    out[row * ND + j] = acc[r2] + bj;
  }
}

extern "C" void kernel_launch(void* const* d_in, const int* in_sizes, int n_in,
                              void* d_out, int out_size, void* d_ws, size_t ws_size,
                              hipStream_t stream) {
  (void)in_sizes; (void)n_in; (void)out_size; (void)ws_size;
  const float* x  = (const float*)d_in[0];
  const float* Wq = (const float*)d_in[1];
  const float* Wk = (const float*)d_in[2];
  const float* Wv = (const float*)d_in[3];
  const float* Wo = (const float*)d_in[4];
  const float* bo = (const float*)d_in[5];
  float* out = (float*)d_out;

  unsigned short* Qp = (unsigned short*)d_ws;   // 8*HS48
  unsigned short* Kp = Qp + 8 * HS48;           // 8*HS48
  unsigned short* Vt = Kp + 8 * HS48;           // 8*VTH
  unsigned short* Op = Vt + 8 * VTH;            // 8*XN bf16 partials
  float* Lp = (float*)(Op + 8 * XN);            // 8*32768 fp32
  // ws use ~31 MB

  proj_qkv_kernel<<<dim3(64, 5, 3), 256, 0, stream>>>(x, Wq, Wk, Wv, Qp, Kp, Vt);
  attn_kernel<<<dim3(2048), 256, 0, stream>>>(Qp, Kp, Vt, Op, Lp);
  proj_out_kernel<<<dim3(64, 5), 256, 0, stream>>>(Op, Lp, Wo, bo, out);
}

// Round 9
// 131.669 us; speedup vs baseline: 1.0285x; 1.0285x over previous
//
#include <hip/hip_runtime.h>
#include <math.h>

// B=1, S=4096, H=8, DH=40, D=320, fp32 in/out.  FOUR kernels:
// proj_qkv: 128x64-tile MFMA GEMM (BK=64, 5 iters) -> Qp/Kp [h][s][48]
//           (Q pre-scaled; pad carries -32 offset), Vt [h][40][4096].
// attn:     MFMA flash (R6 core): ks=8 split, sigma-permuted K so QK C/D
//           regs ARE PV A-frags, p = raw v_exp_f32, l via ones-row,
//           m-tiles processed sequentially (shorter register live ranges).
// combine:  sum 8 bf16 partials, normalize -> Xo [s][320] bf16.
// proj_out: 128x64-tile MFMA GEMM + bias -> out fp32.

#define NS 4096
#define ND 320
#define SCALE2 0.2281101152f      // log2(e)/sqrt(40)
#define HS48 196608               // 4096*48 per head
#define VTH 163840                // 40*4096 per head
#define XN 1310720

typedef __attribute__((ext_vector_type(8))) short bf16x8;
typedef __attribute__((ext_vector_type(16))) float f32x16;

static __device__ __forceinline__ unsigned short f2bru(float f) {
  return (unsigned short)((__builtin_bit_cast(unsigned int, f) + 0x8000u) >> 16);
}
static __device__ __forceinline__ unsigned int pk2ru(float a, float b) {
  unsigned int ua = __builtin_bit_cast(unsigned int, a) + 0x8000u;
  unsigned int ub = __builtin_bit_cast(unsigned int, b) + 0x8000u;
  return __builtin_amdgcn_perm(ub, ua, 0x07060302u);
}
static __device__ __forceinline__ unsigned int pk2t(float a, float b) {
  return __builtin_amdgcn_perm(__builtin_bit_cast(unsigned int, b),
                               __builtin_bit_cast(unsigned int, a), 0x07060302u);
}
static __device__ __forceinline__ float fexp2(float x) {
  return __builtin_amdgcn_exp2f(x);
}
static __device__ __forceinline__ bf16x8 ld8(const unsigned short* p) {
  union { uint2 u[2]; bf16x8 v; } c;
  c.u[0] = *(const uint2*)p;
  c.u[1] = *(const uint2*)(p + 4);
  return c.v;
}
static __device__ __forceinline__ uint4 ld16u(const unsigned short* p) {
  uint2 a = *(const uint2*)p, b = *(const uint2*)(p + 4);
  return make_uint4(a.x, a.y, b.x, b.y);
}
static __device__ __forceinline__ void st16(unsigned short* p, uint4 v) {
  *(uint2*)p = make_uint2(v.x, v.y);
  *(uint2*)(p + 4) = make_uint2(v.z, v.w);
}
// sigma: phys key (0..31) -> MFMA m-row so QK C/D regs land in PV A order
static __device__ __forceinline__ int sig32(int q) {
  int s = q >> 4, h2 = (q >> 3) & 1, j = q & 7;
  return (s << 4) | ((j >> 2) << 3) | (h2 << 2) | (j & 3);
}

// ---------------------------------------------------------------------------
// Kernel 1: q/k/v = x @ W^T. 128x64 tile, BK=64, 5 K-iters. grid (32, 15):
// blockIdx.y -> z = y/5 (Q/K/V), bnn = (y%5)*64. 256 thr = 4 waves, wave w
// owns rows m0=w*32 x all 64 cols (acc0 cols 0-31, acc1 cols 32-63).
// ---------------------------------------------------------------------------
__global__ __launch_bounds__(256) void proj_qkv_kernel(
    const float* __restrict__ x, const float* __restrict__ Wq,
    const float* __restrict__ Wk, const float* __restrict__ Wv,
    unsigned short* __restrict__ Qp, unsigned short* __restrict__ Kp,
    unsigned short* __restrict__ Vt) {
  const int zi = blockIdx.y;
  const int z = zi / 5;
  const int bnn = (zi - z * 5) * 64;
  const float* W = (z == 0) ? Wq : (z == 1) ? Wk : Wv;
  __shared__ __align__(16) unsigned short As[128 * 76];  // stride 38 dw: 2-way
  __shared__ __align__(16) unsigned short Bs[64 * 76];
  const int t = threadIdx.x;
  const int w = t >> 6, l = t & 63, l31 = l & 31, hi = l >> 5;
  const int bm = blockIdx.x * 128;
  const int m0 = w * 32;
  f32x16 acc0 = {0,0,0,0,0,0,0,0,0,0,0,0,0,0,0,0};
  f32x16 acc1 = {0,0,0,0,0,0,0,0,0,0,0,0,0,0,0,0};
  const unsigned short* af = As + (m0 + l31) * 76 + hi * 8;
  const unsigned short* bf0 = Bs + l31 * 76 + hi * 8;
  const unsigned short* bf1 = Bs + (32 + l31) * 76 + hi * 8;
  for (int k0 = 0; k0 < ND; k0 += 64) {
    __syncthreads();
#pragma unroll
    for (int i = 0; i < 4; i++) {            // A: 128 rows x 8 chunks(8)
      int c = t + i * 256;
      int row = c >> 3, kc = (c & 7) << 3;
      const float* g = x + (bm + row) * ND + k0 + kc;
      float4 v0 = *(const float4*)g, v1 = *(const float4*)(g + 4);
      st16(As + row * 76 + kc,
           make_uint4(pk2ru(v0.x, v0.y), pk2ru(v0.z, v0.w),
                      pk2ru(v1.x, v1.y), pk2ru(v1.z, v1.w)));
    }
#pragma unroll
    for (int i = 0; i < 2; i++) {            // B: 64 rows x 8 chunks(8)
      int c = t + i * 256;
      int row = c >> 3, kc = (c & 7) << 3;
      const float* g = W + (bnn + row) * ND + k0 + kc;
      float4 v0 = *(const float4*)g, v1 = *(const float4*)(g + 4);
      st16(Bs + row * 76 + kc,
           make_uint4(pk2ru(v0.x, v0.y), pk2ru(v0.z, v0.w),
                      pk2ru(v1.x, v1.y), pk2ru(v1.z, v1.w)));
    }
    __syncthreads();
#pragma unroll
    for (int ks = 0; ks < 4; ks++) {
      bf16x8 A = ld8(af + ks * 16);
      acc0 = __builtin_amdgcn_mfma_f32_32x32x16_bf16(A, ld8(bf0 + ks * 16), acc0, 0, 0, 0);
      acc1 = __builtin_amdgcn_mfma_f32_32x32x16_bf16(A, ld8(bf1 + ks * 16), acc1, 0, 0, 0);
    }
  }
  __syncthreads();                           // done with As/Bs; reuse as Tile
  if (z < 2) {
    // ---- Q/K epilogue: Tile [128 rows][64 cols] stride 68 over As ----
    unsigned short* Tile = As;
    unsigned short* Y = (z == 0) ? Qp : Kp;
    const float sc = (z == 0) ? SCALE2 : 1.0f;
    const unsigned int padw = (z == 0) ? 0xC200u : 0x3F80u;  // -32.0 : 1.0
#pragma unroll
    for (int r2 = 0; r2 < 16; r2++) {
      int lr = m0 + (r2 & 3) + 8 * (r2 >> 2) + 4 * hi;
      Tile[lr * 68 + l31] = f2bru(acc0[r2] * sc);
      Tile[lr * 68 + 32 + l31] = f2bru(acc1[r2] * sc);
    }
    __syncthreads();
#pragma unroll
    for (int i = 0; i < 4; i++) {            // 128 rows x 8 chunks
      int c = t + i * 256;
      int row = c >> 3, ch = c & 7;
      int j = bnn + ch * 8;
      int h = j / 40, dh = j - h * 40;
      uint4 v = ld16u(Tile + row * 68 + ch * 8);
      st16(Y + h * HS48 + (bm + row) * 48 + dh, v);
      if (dh == 0)
        st16(Y + h * HS48 + (bm + row) * 48 + 40, make_uint4(padw, 0u, 0u, 0u));
    }
  } else {
    // ---- V epilogue: transposed Tile [64 j][128 s] stride 132 over As ----
    unsigned short* Tile = As;
#pragma unroll
    for (int r2 = 0; r2 < 16; r2++) {
      int lr = m0 + (r2 & 3) + 8 * (r2 >> 2) + 4 * hi;
      Tile[l31 * 132 + lr] = f2bru(acc0[r2]);
      Tile[(32 + l31) * 132 + lr] = f2bru(acc1[r2]);
    }
    __syncthreads();
#pragma unroll
    for (int i = 0; i < 4; i++) {            // 64 j-rows x 16 s-chunks
      int c = t + i * 256;
      int row = c >> 4, ch = c & 15;
      int j = bnn + row;
      int h = j / 40, dd = j - h * 40;
      uint4 v = ld16u(Tile + row * 132 + ch * 8);
      st16(Vt + h * VTH + dd * NS + bm + ch * 8, v);
    }
  }
}

// ---------------------------------------------------------------------------
// Kernel 2: MFMA flash attention. grid 2048 x 256 (R6 core, sequential
// m-tiles). h=b&7 XCD swizzle, ks=8 splits, 8 iters of 64-key tiles.
// ---------------------------------------------------------------------------
__global__ __launch_bounds__(256) void attn_kernel(
    const unsigned short* __restrict__ Qp, const unsigned short* __restrict__ Kp,
    const unsigned short* __restrict__ Vt, unsigned short* __restrict__ Op,
    float* __restrict__ Lp) {
  const int b = blockIdx.x;
  const int h = b & 7, ks = (b >> 3) & 7, qt = b >> 6;
  const int t = threadIdx.x;
  const int w = t >> 6, l = t & 63, l31 = l & 31, hi = l >> 5;
  __shared__ __align__(16) unsigned short Ks[64 * 68];   // [m-row][48 used]
  __shared__ __align__(16) unsigned short Vs[48 * 68];   // [dh][64 keys]
  for (int i = t; i < 272; i += 256)
    ((unsigned int*)(Vs + 40 * 68))[i] = (i < 34) ? 0x3F803F80u : 0u;

  const int kbase = ks * 512;
  const int qbase = qt * 128 + w * 32;
  const unsigned short* qp = Qp + h * HS48 + (qbase + l31) * 48 + hi * 8;
  bf16x8 qf0 = *(const bf16x8*)qp;
  bf16x8 qf1 = *(const bf16x8*)(qp + 16);
  bf16x8 qf2 = *(const bf16x8*)(qp + 32);   // includes {-32,0..} pad

  f32x16 oa0 = {0,0,0,0,0,0,0,0,0,0,0,0,0,0,0,0};
  f32x16 oa1 = {0,0,0,0,0,0,0,0,0,0,0,0,0,0,0,0};

  const int kr0 = t / 6, kc0 = t - kr0 * 6;
  const int kr1 = (t + 256) / 6, kc1 = (t + 256) - kr1 * 6;
  const unsigned short* gK0 = Kp + h * HS48 + (kbase + kr0) * 48 + kc0 * 8;
  const unsigned short* gK1 = Kp + h * HS48 + (kbase + kr1) * 48 + kc1 * 8;
  unsigned short* lK0 = Ks + ((kr0 & 32) | sig32(kr0 & 31)) * 68 + kc0 * 8;
  unsigned short* lK1 = Ks + ((kr1 & 32) | sig32(kr1 & 31)) * 68 + kc1 * 8;
  const int vr0 = t >> 3, vc = t & 7, vr1 = 32 + vr0;
  const unsigned short* gV0 = Vt + h * VTH + vr0 * NS + kbase + vc * 8;
  const unsigned short* gV1 = Vt + h * VTH + vr1 * NS + kbase + vc * 8;
  unsigned short* lV0 = Vs + vr0 * 68 + vc * 8;
  unsigned short* lV1 = Vs + vr1 * 68 + vc * 8;

  const unsigned short* kf0 = Ks + l31 * 68 + hi * 8;
  const unsigned short* kf1 = Ks + (32 + l31) * 68 + hi * 8;
  const unsigned short* vf0 = Vs + l31 * 68 + hi * 8;
  const unsigned short* vf1 = Vs + (32 + (l31 & 15)) * 68 + hi * 8;

  uint4 ka = *(const uint4*)gK0;
  uint4 kb2, vb2;
  uint4 va = *(const uint4*)gV0;
  if (t < 128) kb2 = *(const uint4*)gK1;
  if (t < 64)  vb2 = *(const uint4*)gV1;

  for (int it = 0; it < 8; ++it) {
    __syncthreads();
    st16(lK0, ka);
    if (t < 128) st16(lK1, kb2);
    st16(lV0, va);
    if (t < 64) st16(lV1, vb2);
    __syncthreads();
    // prefetch next tile (last-iter overrun lands in adjacent ws buffers)
    gK0 += 64 * 48; gK1 += 64 * 48; gV0 += 64; gV1 += 64;
    ka = *(const uint4*)gK0;
    va = *(const uint4*)gV0;
    if (t < 128) kb2 = *(const uint4*)gK1;
    if (t < 64)  vb2 = *(const uint4*)gV1;

    {  // m-tile 0: phys keys 0..31 (sigma rows)
      f32x16 s0 = {0,0,0,0,0,0,0,0,0,0,0,0,0,0,0,0};
      s0 = __builtin_amdgcn_mfma_f32_32x32x16_bf16(ld8(kf0), qf0, s0, 0, 0, 0);
      s0 = __builtin_amdgcn_mfma_f32_32x32x16_bf16(ld8(kf0 + 16), qf1, s0, 0, 0, 0);
      s0 = __builtin_amdgcn_mfma_f32_32x32x16_bf16(ld8(kf0 + 32), qf2, s0, 0, 0, 0);
      unsigned int pw[8];
#pragma unroll
      for (int i = 0; i < 8; i++)
        pw[i] = pk2t(fexp2(s0[2 * i]), fexp2(s0[2 * i + 1]));
      bf16x8 pf0 = __builtin_bit_cast(bf16x8, make_uint4(pw[0], pw[1], pw[2], pw[3]));
      bf16x8 pf1 = __builtin_bit_cast(bf16x8, make_uint4(pw[4], pw[5], pw[6], pw[7]));
      oa0 = __builtin_amdgcn_mfma_f32_32x32x16_bf16(pf0, ld8(vf0), oa0, 0, 0, 0);
      oa1 = __builtin_amdgcn_mfma_f32_32x32x16_bf16(pf0, ld8(vf1), oa1, 0, 0, 0);
      oa0 = __builtin_amdgcn_mfma_f32_32x32x16_bf16(pf1, ld8(vf0 + 16), oa0, 0, 0, 0);
      oa1 = __builtin_amdgcn_mfma_f32_32x32x16_bf16(pf1, ld8(vf1 + 16), oa1, 0, 0, 0);
    }
    {  // m-tile 1: phys keys 32..63
      f32x16 s1 = {0,0,0,0,0,0,0,0,0,0,0,0,0,0,0,0};
      s1 = __builtin_amdgcn_mfma_f32_32x32x16_bf16(ld8(kf1), qf0, s1, 0, 0, 0);
      s1 = __builtin_amdgcn_mfma_f32_32x32x16_bf16(ld8(kf1 + 16), qf1, s1, 0, 0, 0);
      s1 = __builtin_amdgcn_mfma_f32_32x32x16_bf16(ld8(kf1 + 32), qf2, s1, 0, 0, 0);
      unsigned int pw[8];
#pragma unroll
      for (int i = 0; i < 8; i++)
        pw[i] = pk2t(fexp2(s1[2 * i]), fexp2(s1[2 * i + 1]));
      bf16x8 pf2 = __builtin_bit_cast(bf16x8, make_uint4(pw[0], pw[1], pw[2], pw[3]));
      bf16x8 pf3 = __builtin_bit_cast(bf16x8, make_uint4(pw[4], pw[5], pw[6], pw[7]));
      oa0 = __builtin_amdgcn_mfma_f32_32x32x16_bf16(pf2, ld8(vf0 + 32), oa0, 0, 0, 0);
      oa1 = __builtin_amdgcn_mfma_f32_32x32x16_bf16(pf2, ld8(vf1 + 32), oa1, 0, 0, 0);
      oa0 = __builtin_amdgcn_mfma_f32_32x32x16_bf16(pf3, ld8(vf0 + 48), oa0, 0, 0, 0);
      oa1 = __builtin_amdgcn_mfma_f32_32x32x16_bf16(pf3, ld8(vf1 + 48), oa1, 0, 0, 0);
    }
  }

  unsigned short* opb = Op + ks * XN + h * 163840;
  float* lpb = Lp + ks * 32768 + h * NS;
#pragma unroll
  for (int r2 = 0; r2 < 16; r2++) {
    int qr = qbase + (r2 & 3) + 8 * (r2 >> 2) + 4 * hi;
    opb[qr * 40 + l31] = f2bru(oa0[r2]);
    if (l31 < 8) opb[qr * 40 + 32 + l31] = f2bru(oa1[r2]);
    if (l31 == 8) lpb[qr] = oa1[r2];   // l = Sum(p) via ones-row at dh=40
  }
}

// ---------------------------------------------------------------------------
// Kernel 3: sum 8 bf16 partials, normalize -> Xo [s][320] bf16.
// grid 2560 x 256, 2 elems/thread.
// ---------------------------------------------------------------------------
__global__ __launch_bounds__(256) void combine_kernel(
    const unsigned short* __restrict__ Op, const float* __restrict__ Lp,
    unsigned short* __restrict__ Xo) {
  int e = (blockIdx.x * 256 + threadIdx.x) * 2;    // over [h][s][40]
  int h = e / 163840;
  int r = e - h * 163840;
  int s = r / 40;
  int dh = r - s * 40;
  float a0 = 0.f, a1 = 0.f, lsum = 0.f;
#pragma unroll
  for (int k = 0; k < 8; k++) {
    unsigned int u = *(const unsigned int*)(Op + k * XN + e);
    a0 += __builtin_bit_cast(float, u << 16);
    a1 += __builtin_bit_cast(float, u & 0xFFFF0000u);
    lsum += Lp[k * 32768 + h * NS + s];
  }
  float inv = 1.0f / lsum;
  *(unsigned int*)(Xo + s * ND + h * 40 + dh) = pk2ru(a0 * inv, a1 * inv);
}

// ---------------------------------------------------------------------------
// Kernel 4: out = Xo @ Wo^T + bo. 128x64 tile, BK=64, 5 iters. grid (32, 5).
// ---------------------------------------------------------------------------
__global__ __launch_bounds__(256) void proj_out_kernel(
    const unsigned short* __restrict__ Xo, const float* __restrict__ Wo,
    const float* __restrict__ bo, float* __restrict__ out) {
  __shared__ __align__(16) unsigned short As[128 * 76];
  __shared__ __align__(16) unsigned short Bs[64 * 76];
  const int t = threadIdx.x;
  const int w = t >> 6, l = t & 63, l31 = l & 31, hi = l >> 5;
  const int bm = blockIdx.x * 128;
  const int bnn = blockIdx.y * 64;
  const int m0 = w * 32;
  f32x16 acc0 = {0,0,0,0,0,0,0,0,0,0,0,0,0,0,0,0};
  f32x16 acc1 = {0,0,0,0,0,0,0,0,0,0,0,0,0,0,0,0};
  const unsigned short* af = As + (m0 + l31) * 76 + hi * 8;
  const unsigned short* bf0 = Bs + l31 * 76 + hi * 8;
  const unsigned short* bf1 = Bs + (32 + l31) * 76 + hi * 8;
  for (int k0 = 0; k0 < ND; k0 += 64) {
    __syncthreads();
#pragma unroll
    for (int i = 0; i < 4; i++) {            // A: 128 rows x 8 chunks, bf16 src
      int c = t + i * 256;
      int row = c >> 3, kc = (c & 7) << 3;
      uint4 v = *(const uint4*)(Xo + (bm + row) * ND + k0 + kc);
      st16(As + row * 76 + kc, v);
    }
#pragma unroll
    for (int i = 0; i < 2; i++) {            // B: 64 rows x 8 chunks, fp32 src
      int c = t + i * 256;
      int row = c >> 3, kc = (c & 7) << 3;
      const float* g = Wo + (bnn + row) * ND + k0 + kc;
      float4 v0 = *(const float4*)g, v1 = *(const float4*)(g + 4);
      st16(Bs + row * 76 + kc,
           make_uint4(pk2ru(v0.x, v0.y), pk2ru(v0.z, v0.w),
                      pk2ru(v1.x, v1.y), pk2ru(v1.z, v1.w)));
    }
    __syncthreads();
#pragma unroll
    for (int ks = 0; ks < 4; ks++) {
      bf16x8 A = ld8(af + ks * 16);
      acc0 = __builtin_amdgcn_mfma_f32_32x32x16_bf16(A, ld8(bf0 + ks * 16), acc0, 0, 0, 0);
      acc1 = __builtin_amdgcn_mfma_f32_32x32x16_bf16(A, ld8(bf1 + ks * 16), acc1, 0, 0, 0);
    }
  }
  const int j0 = bnn + l31, j1 = bnn + 32 + l31;
  const float bj0 = bo[j0], bj1 = bo[j1];
#pragma unroll
  for (int r2 = 0; r2 < 16; r2++) {
    int row = bm + m0 + (r2 & 3) + 8 * (r2 >> 2) + 4 * hi;
    out[row * ND + j0] = acc0[r2] + bj0;
    out[row * ND + j1] = acc1[r2] + bj1;
  }
}

extern "C" void kernel_launch(void* const* d_in, const int* in_sizes, int n_in,
                              void* d_out, int out_size, void* d_ws, size_t ws_size,
                              hipStream_t stream) {
  (void)in_sizes; (void)n_in; (void)out_size; (void)ws_size;
  const float* x  = (const float*)d_in[0];
  const float* Wq = (const float*)d_in[1];
  const float* Wk = (const float*)d_in[2];
  const float* Wv = (const float*)d_in[3];
  const float* Wo = (const float*)d_in[4];
  const float* bo = (const float*)d_in[5];
  float* out = (float*)d_out;

  unsigned short* Qp = (unsigned short*)d_ws;   // 8*HS48
  unsigned short* Kp = Qp + 8 * HS48;           // 8*HS48
  unsigned short* Vt = Kp + 8 * HS48;           // 8*VTH
  unsigned short* Xo = Vt + 8 * VTH;            // XN
  unsigned short* Op = Xo + XN;                 // 8*XN bf16 partials
  float* Lp = (float*)(Op + 8 * XN);            // 8*32768 fp32
  // ws use ~34 MB

  proj_qkv_kernel<<<dim3(32, 15), 256, 0, stream>>>(x, Wq, Wk, Wv, Qp, Kp, Vt);
  attn_kernel<<<dim3(2048), 256, 0, stream>>>(Qp, Kp, Vt, Op, Lp);
  combine_kernel<<<dim3(2560), 256, 0, stream>>>(Op, Lp, Xo);
  proj_out_kernel<<<dim3(32, 5), 256, 0, stream>>>(Xo, Wo, bo, out);
}